// Round 1
// baseline (330.040 us; speedup 1.0000x reference)
//
#include <hip/hip_runtime.h>
#include <math.h>

// Output row layout (70 floats): [coords(3) | enc(64) | colours(3)]
// enc[2j]   = sin(i / 10000^(j/32))
// enc[2j+1] = cos(i / 10000^(j/32))
// MAX_RANGE = 1.0 (no-op scale).

#define OUTC 70

__global__ __launch_bounds__(256) void pe_kernel(const float* __restrict__ pc,
                                                 float* __restrict__ out,
                                                 long long total) {
    __shared__ double s_invfreq[32];
    const int tid = threadIdx.x;
    if (tid < 32) {
        // 1 / 10000^(j/32), exact in double (rel err ~1e-16, negligible vs f32 ulp)
        s_invfreq[tid] = exp(-(double)tid * (log(10000.0) / 32.0));
    }
    __syncthreads();

    const long long base = ((long long)blockIdx.x * blockDim.x + tid) * 4;
    if (base >= total) return;

    const double two_pi     = 6.283185307179586476925286766559;
    const double inv_two_pi = 0.15915494309189533576888376337251;

    float4 v;
    float* ve = &v.x;

#pragma unroll
    for (int k = 0; k < 4; ++k) {
        const long long idx = base + k;
        const int row = (int)(idx / OUTC);           // magic-mul div by const
        const int col = (int)(idx - (long long)row * OUTC);
        float r;
        if (col < 3) {
            r = pc[row * 6 + col];                   // coords
        } else if (col >= 67) {
            r = pc[row * 6 + (col - 64)];            // colours (col-67+3)
        } else {
            const int e = col - 3;                   // 0..63
            const int j = e >> 1;                    // 0..31
            const double arg = (double)row * s_invfreq[j];
            // range-reduce in double: red = arg - round(arg/2pi)*2pi, |red| <= pi
            const double kk  = rint(arg * inv_two_pi);
            const double red = fma(-kk, two_pi, arg);
            const float rf = (float)red;
            float s, c;
            __sincosf(rf, &s, &c);                   // accurate on [-pi, pi]
            r = (e & 1) ? c : s;
        }
        ve[k] = r;
    }

    const long long last = base + 3;
    if (last < total) {
        reinterpret_cast<float4*>(out)[base >> 2] = v;   // 16B coalesced store
    } else {
        for (int k = 0; k < 4; ++k)
            if (base + k < total) out[base + k] = ve[k];
    }
}

extern "C" void kernel_launch(void* const* d_in, const int* in_sizes, int n_in,
                              void* d_out, int out_size, void* d_ws, size_t ws_size,
                              hipStream_t stream) {
    const float* pc = (const float*)d_in[0];
    float* out = (float*)d_out;
    const long long n = in_sizes[0] / 6;          // rows
    const long long total = n * OUTC;             // output elements (== out_size)
    const long long n_threads = (total + 3) / 4;
    const int block = 256;
    const long long grid = (n_threads + block - 1) / block;
    pe_kernel<<<dim3((unsigned)grid), dim3(block), 0, stream>>>(pc, out, total);
}